// Round 20
// baseline (65.703 us; speedup 1.0000x reference)
//
#include <hip/hip_runtime.h>
#include <hip/hip_bf16.h>

#define D 128
#define H 256
#define NB 32
#define NN 128

typedef __attribute__((ext_vector_type(8))) _Float16 f16x8;
typedef __attribute__((ext_vector_type(4))) float f32x4;
typedef __attribute__((ext_vector_type(16))) float f32x16;
typedef __attribute__((ext_vector_type(4))) unsigned int uint4v;

__device__ __forceinline__ unsigned short to_f16u(float f) {
  _Float16 h = (_Float16)f;
  return __builtin_bit_cast(unsigned short, h);
}

// packed f32x2 -> f16x2: v_cvt_pkrtz_f16_f32 (verified R17)
__device__ __forceinline__ unsigned cvt_pk_f16(float lo, float hi) {
  unsigned d;
  asm("v_cvt_pkrtz_f16_f32 %0, %1, %2" : "=v"(d) : "v"(lo), "v"(hi));
  return d;
}

// packed f16 add (verified R17); v_pk_add_bf16 does NOT exist (R10)
__device__ __forceinline__ unsigned pk_add_f16(unsigned a, unsigned b) {
  unsigned d;
  asm("v_pk_add_f16 %0, %1, %2" : "=v"(d) : "v"(a), "v"(b));
  return d;
}

// packed relu: signed-i16 max with 0 (verified R7-R17)
__device__ __forceinline__ unsigned pk_relu(unsigned x) {
  unsigned d;
  asm("v_pk_max_i16 %0, %1, %2" : "=v"(d) : "v"(x), "v"(0u));
  return d;
}

// ---------------- Kernel 0: repack all weights to f16 MFMA B-fragment order ----
// 16x16x32 frag (w1f/w3f/w4f): lane l, e -> W[ks*32+(l>>4)*8+e][nt*16+(l&15)]
// 32x32x16 frag (bw2): tile t=(st,ntile): lane l, e ->
//   W[st*16 + (l>>5)*8 + e][ntile*32 + (l&31)]
__global__ __launch_bounds__(512) void k_repack(
    const float* __restrict__ mw1, const float* __restrict__ uw1,
    const float* __restrict__ uw2, const float* __restrict__ mw2,
    unsigned short* __restrict__ w1f, unsigned short* __restrict__ w3f,
    unsigned short* __restrict__ w4f, unsigned short* __restrict__ bw2) {
  const int gt = blockIdx.x * 512 + threadIdx.x;
  const int tile = gt >> 6, l = gt & 63;
  const int lg = l >> 4, l15 = l & 15;
  if (tile < 128) {
    const int ks = tile >> 5, ntg = tile & 31;
#pragma unroll
    for (int e = 0; e < 8; ++e) {
      int k = ks * 32 + lg * 8 + e;
      int col = ntg * 16 + l15;
      float v = (col < 256) ? mw1[k * 256 + col] : mw1[(128 + k) * 256 + (col - 256)];
      w1f[(size_t)(tile * 64 + l) * 8 + e] = to_f16u(v);
    }
  } else if (tile < 256) {
    const int t = tile - 128, ks = t >> 4, ntg = t & 15;
#pragma unroll
    for (int e = 0; e < 8; ++e) {
      int k = ks * 32 + lg * 8 + e;
      w3f[(size_t)(t * 64 + l) * 8 + e] = to_f16u(uw1[k * 256 + ntg * 16 + l15]);
    }
  } else if (tile < 320) {
    const int t = tile - 256, ks = t >> 3, ntg = t & 7;
#pragma unroll
    for (int e = 0; e < 8; ++e) {
      int k = ks * 32 + lg * 8 + e;
      w4f[(size_t)(t * 64 + l) * 8 + e] = to_f16u(uw2[k * 128 + ntg * 16 + l15]);
    }
  } else {
    const int t = tile - 320;            // 0..63: st = t>>2, ntile = t&3
    const int st = t >> 2, ntile = t & 3;
    const int lh = l >> 5, l31 = l & 31;
#pragma unroll
    for (int e = 0; e < 8; ++e) {
      int k = st * 16 + lh * 8 + e;
      bw2[(size_t)(t * 64 + l) * 8 + e] = to_f16u(mw2[k * 128 + ntile * 32 + l31]);
    }
  }
}

// ---------------- Kernel 1: LN*mask -> f16 + projection GEMM via MFMA (R18) ----
__global__ __launch_bounds__(256) void k_ln_proj(
    const float* __restrict__ nodes, const float* __restrict__ node_mask,
    const float* __restrict__ ln_g, const float* __restrict__ ln_b,
    const unsigned short* __restrict__ w1f,
    float* __restrict__ xi_p, unsigned short* __restrict__ xjh) {
  const int row0 = blockIdx.x * 16;
  const int half = blockIdx.y;
  const int tid = threadIdx.x;
  __shared__ unsigned short xh[16 * 128];   // f16, 16B-group swizzled

  {
    const int r = tid >> 4, l16 = tid & 15, d0 = l16 * 8;
    float4 v0 = *(const float4*)(nodes + (size_t)(row0 + r) * D + d0);
    float4 v1 = *(const float4*)(nodes + (size_t)(row0 + r) * D + d0 + 4);
    float s1 = v0.x + v0.y + v0.z + v0.w + v1.x + v1.y + v1.z + v1.w;
    float s2 = v0.x * v0.x + v0.y * v0.y + v0.z * v0.z + v0.w * v0.w +
               v1.x * v1.x + v1.y * v1.y + v1.z * v1.z + v1.w * v1.w;
#pragma unroll
    for (int off = 1; off < 16; off <<= 1) {
      s1 += __shfl_xor(s1, off);
      s2 += __shfl_xor(s2, off);
    }
    float mu = s1 * (1.0f / 128.0f);
    float var = s2 * (1.0f / 128.0f) - mu * mu;
    float rsig = rsqrtf(var + 1e-5f);
    float m = node_mask[row0 + r];
    float4 g0 = *(const float4*)(ln_g + d0), g1 = *(const float4*)(ln_g + d0 + 4);
    float4 b0 = *(const float4*)(ln_b + d0), b1 = *(const float4*)(ln_b + d0 + 4);
    float x0 = ((v0.x - mu) * rsig * g0.x + b0.x) * m;
    float x1 = ((v0.y - mu) * rsig * g0.y + b0.y) * m;
    float x2 = ((v0.z - mu) * rsig * g0.z + b0.z) * m;
    float x3 = ((v0.w - mu) * rsig * g0.w + b0.w) * m;
    float x4 = ((v1.x - mu) * rsig * g1.x + b1.x) * m;
    float x5 = ((v1.y - mu) * rsig * g1.y + b1.y) * m;
    float x6 = ((v1.z - mu) * rsig * g1.z + b1.z) * m;
    float x7 = ((v1.w - mu) * rsig * g1.w + b1.w) * m;
    uint4v u;
    u[0] = cvt_pk_f16(x0, x1); u[1] = cvt_pk_f16(x2, x3);
    u[2] = cvt_pk_f16(x4, x5); u[3] = cvt_pk_f16(x6, x7);
    const int g = l16 ^ (r & 7);          // swizzled 16B-group index
    *(uint4v*)(&xh[r * 128 + g * 8]) = u;
  }
  __syncthreads();

  const int w = tid >> 6, l = tid & 63;
  const int lg = l >> 4, l15 = l & 15;
  f32x4 acc[4];
#pragma unroll
  for (int nt = 0; nt < 4; ++nt) acc[nt] = (f32x4){0.f, 0.f, 0.f, 0.f};

#pragma unroll
  for (int ks = 0; ks < 4; ++ks) {
    const int g = (ks * 4 + lg) ^ (l15 & 7);
    f16x8 a = *(const f16x8*)(&xh[l15 * 128 + g * 8]);
#pragma unroll
    for (int nt = 0; nt < 4; ++nt) {
      const int tile = ks * 32 + half * 16 + w * 4 + nt;
      f16x8 bf = *(const f16x8*)(w1f + (size_t)(tile * 64 + l) * 8);
      acc[nt] = __builtin_amdgcn_mfma_f32_16x16x32_f16(a, bf, acc[nt], 0, 0, 0);
    }
  }

  if (half == 0) {
#pragma unroll
    for (int nt = 0; nt < 4; ++nt)
#pragma unroll
      for (int r = 0; r < 4; ++r)
        xi_p[(size_t)(row0 + lg * 4 + r) * H + w * 64 + nt * 16 + l15] = acc[nt][r];
  } else {
#pragma unroll
    for (int nt = 0; nt < 4; ++nt)
#pragma unroll
      for (int r = 0; r < 4; ++r)
        xjh[(size_t)(row0 + lg * 4 + r) * H + w * 64 + nt * 16 + l15] = to_f16u(acc[nt][r]);
  }
}

// ---------------- Kernel 2: msgs GEMM via 32x32x16 MFMA, B shared over 2 i ----
// R20: wave = (j-slab, n-half), computes BOTH i's. Per st: 1 xu load (shared),
// 2 A-builds (differ by cs2 only), 2 bf reads feeding 4 MFMAs -> block B-LDS
// reads halve 512 -> 256 (the ~20us dominant pipe), xu L2 unchanged.
// acc = 2i x 2nt x 16 = 64 AGPRs (same budget). C map m74/m101:
// col = ntile*32 + l31, j = jbase + 4*(l>>5) + (reg&3) + 8*(reg>>2).
// Lessons: no TM growth (R4/R7/R9/R11), B in LDS (R12), no cross-block
// A-build dup (R15). Spill tripwire: WRITE_SIZE ~2MB.
__global__ __launch_bounds__(512, 4) void k_msgs(
    const float* __restrict__ xi_p, const unsigned short* __restrict__ xjh,
    const unsigned short* __restrict__ bw2g, const float* __restrict__ mb1,
    const float* __restrict__ mb2, const float* __restrict__ node_mask,
    float* __restrict__ agg) {
  const int b = blockIdx.y;
  const int i0 = blockIdx.x * 2;
  const int tid = threadIdx.x;           // 0..511
  const int w = tid >> 6, l = tid & 63;  // 8 waves
  const int jslab = w >> 1;              // 0..3: 32-row j-slab
  const int nh = w & 1;                  // 0..1: 64-col n-half
  const int jbase = jslab * 32;
  const int l31 = l & 31, lh = l >> 5;

  __shared__ unsigned short bw2s[32768]; // 64 KB B fragments (64 tiles x 1KB)
  __shared__ unsigned cs2[2][128];       // f16-pair (xi_p + mb1), per i
  __shared__ float mb2s[128], maskS[128];
  __shared__ float waveAgg[8][2][64];

  {
    const uint4v* src = (const uint4v*)bw2g;
    uint4v* dst = (uint4v*)bw2s;
#pragma unroll
    for (int c = 0; c < 8; ++c) dst[c * 512 + tid] = src[c * 512 + tid];
  }
  if (tid < 256) {
    int ii = tid >> 7, p = tid & 127;
    float2 xi2 = *(const float2*)(xi_p + (size_t)(b * NN + i0 + ii) * H + 2 * p);
    float2 mbv = *(const float2*)(mb1 + 2 * p);
    cs2[ii][p] = cvt_pk_f16(xi2.x + mbv.x, xi2.y + mbv.y);
  }
  if (tid < 128) { mb2s[tid] = mb2[tid]; maskS[tid] = node_mask[b * NN + tid]; }
  __syncthreads();

  const unsigned short* xrow = xjh + (size_t)(b * NN + jbase + l31) * H;

  f32x16 acc[2][2];                      // [i][ntile]
#pragma unroll
  for (int ii = 0; ii < 2; ++ii)
#pragma unroll
    for (int nt = 0; nt < 2; ++nt)
#pragma unroll
      for (int r = 0; r < 16; ++r) acc[ii][nt][r] = 0.f;

  const uint4v* bfrag = (const uint4v*)bw2s;

#pragma unroll
  for (int st = 0; st < 16; ++st) {
    const int kb = st * 16 + lh * 8;     // f16-elem k offset
    uint4v xu = *(const uint4v*)(xrow + kb);
    uint4v cc0 = *(const uint4v*)(&cs2[0][kb >> 1]);
    uint4v cc1 = *(const uint4v*)(&cs2[1][kb >> 1]);
    uint4v a0, a1;
#pragma unroll
    for (int p = 0; p < 4; ++p) {
      a0[p] = pk_relu(pk_add_f16(xu[p], cc0[p]));
      a1[p] = pk_relu(pk_add_f16(xu[p], cc1[p]));
    }
    f16x8 af0 = __builtin_bit_cast(f16x8, a0);
    f16x8 af1 = __builtin_bit_cast(f16x8, a1);
#pragma unroll
    for (int nt = 0; nt < 2; ++nt) {
      f16x8 bf = __builtin_bit_cast(f16x8, bfrag[(st * 4 + nh * 2 + nt) * 64 + l]);
      acc[0][nt] = __builtin_amdgcn_mfma_f32_32x32x16_f16(af0, bf, acc[0][nt], 0, 0, 0);
      acc[1][nt] = __builtin_amdgcn_mfma_f32_32x32x16_f16(af1, bf, acc[1][nt], 0, 0, 0);
    }
  }

  // Epilogue: relu(acc+mb2)*mask_j, column-sum over the tile's 32 j rows.
#pragma unroll
  for (int ii = 0; ii < 2; ++ii)
#pragma unroll
    for (int nt = 0; nt < 2; ++nt) {
      const float bias = mb2s[nh * 64 + nt * 32 + l31];
      float s = 0.f;
#pragma unroll
      for (int reg = 0; reg < 16; ++reg) {
        const int j = jbase + 4 * lh + (reg & 3) + 8 * (reg >> 2);
        s = fmaf(fmaxf(acc[ii][nt][reg] + bias, 0.f), maskS[j], s);
      }
      s += __shfl_xor(s, 32);
      if (l < 32) waveAgg[w][ii][nt * 32 + l31] = s;
    }
  __syncthreads();
  if (tid < 256) {
    const int ii = tid >> 7, col = tid & 127;  // 2 i's x 128 cols
    const int nh2 = col >> 6, c6 = col & 63;
    agg[(size_t)(b * NN + i0 + ii) * D + col] =
        waveAgg[nh2][ii][c6] + waveAgg[2 + nh2][ii][c6] +
        waveAgg[4 + nh2][ii][c6] + waveAgg[6 + nh2][ii][c6];
  }
}

// ---------------- Kernel 3: update MLP via MFMA + residual + mask (R18) --------
__global__ __launch_bounds__(256) void k_upd(
    const float* __restrict__ nodes, const float* __restrict__ agg,
    const unsigned short* __restrict__ w3f, const float* __restrict__ ub1,
    const unsigned short* __restrict__ w4f, const float* __restrict__ ub2,
    const float* __restrict__ node_mask, float* __restrict__ out) {
  const int row0 = blockIdx.x * 16;
  const int tid = threadIdx.x;
  __shared__ unsigned short ah[16 * 256];  // f16 [16][32 groups], swizzled
  __shared__ unsigned short uh[16 * 256];  // f16 u, swizzled
  __shared__ float ns[16][128];
  __shared__ float msk[16];

  {
    const int r = tid >> 4, l16 = tid & 15, d0 = l16 * 8;
    float4 n0 = *(const float4*)(nodes + (size_t)(row0 + r) * D + d0);
    float4 n1 = *(const float4*)(nodes + (size_t)(row0 + r) * D + d0 + 4);
    *(float4*)(&ns[r][d0]) = n0;
    *(float4*)(&ns[r][d0 + 4]) = n1;
    uint4v u;
    u[0] = cvt_pk_f16(n0.x, n0.y); u[1] = cvt_pk_f16(n0.z, n0.w);
    u[2] = cvt_pk_f16(n1.x, n1.y); u[3] = cvt_pk_f16(n1.z, n1.w);
    int g = l16 ^ (r & 7);
    *(uint4v*)(&ah[r * 256 + g * 8]) = u;
    float4 a0 = *(const float4*)(agg + (size_t)(row0 + r) * D + d0);
    float4 a1 = *(const float4*)(agg + (size_t)(row0 + r) * D + d0 + 4);
    u[0] = cvt_pk_f16(a0.x, a0.y); u[1] = cvt_pk_f16(a0.z, a0.w);
    u[2] = cvt_pk_f16(a1.x, a1.y); u[3] = cvt_pk_f16(a1.z, a1.w);
    g = (16 + l16) ^ (r & 7);
    *(uint4v*)(&ah[r * 256 + g * 8]) = u;
    if (tid < 16) msk[tid] = node_mask[row0 + tid];
  }
  __syncthreads();

  const int w = tid >> 6, l = tid & 63;
  const int lg = l >> 4, l15 = l & 15;

  // GEMM1: 16 x 256, K=256
  f32x4 acc[4];
#pragma unroll
  for (int nt = 0; nt < 4; ++nt) acc[nt] = (f32x4){0.f, 0.f, 0.f, 0.f};
#pragma unroll
  for (int ks = 0; ks < 8; ++ks) {
    const int g = (ks * 4 + lg) ^ (l15 & 7);
    f16x8 a = *(const f16x8*)(&ah[l15 * 256 + g * 8]);
#pragma unroll
    for (int nt = 0; nt < 4; ++nt) {
      const int tile = ks * 16 + w * 4 + nt;
      f16x8 bf = *(const f16x8*)(w3f + (size_t)(tile * 64 + l) * 8);
      acc[nt] = __builtin_amdgcn_mfma_f32_16x16x32_f16(a, bf, acc[nt], 0, 0, 0);
    }
  }
  // u = relu(acc + ub1) -> uh (swizzled scalar stores)
#pragma unroll
  for (int nt = 0; nt < 4; ++nt) {
    const int col = w * 64 + nt * 16 + l15;
    const float bias = ub1[col];
#pragma unroll
    for (int r = 0; r < 4; ++r) {
      const int row = lg * 4 + r;
      const int g = (col >> 3) ^ (row & 7);
      uh[row * 256 + g * 8 + (col & 7)] = to_f16u(fmaxf(acc[nt][r] + bias, 0.f));
    }
  }
  __syncthreads();

  // GEMM2: 16 x 128, K=256
  f32x4 acc2[2];
  acc2[0] = (f32x4){0.f, 0.f, 0.f, 0.f};
  acc2[1] = (f32x4){0.f, 0.f, 0.f, 0.f};
#pragma unroll
  for (int ks = 0; ks < 8; ++ks) {
    const int g = (ks * 4 + lg) ^ (l15 & 7);
    f16x8 a = *(const f16x8*)(&uh[l15 * 256 + g * 8]);
#pragma unroll
    for (int nt = 0; nt < 2; ++nt) {
      const int tile = ks * 8 + w * 2 + nt;
      f16x8 bf = *(const f16x8*)(w4f + (size_t)(tile * 64 + l) * 8);
      acc2[nt] = __builtin_amdgcn_mfma_f32_16x16x32_f16(a, bf, acc2[nt], 0, 0, 0);
    }
  }
#pragma unroll
  for (int nt = 0; nt < 2; ++nt) {
    const int col = w * 32 + nt * 16 + l15;
    const float ub2v = ub2[col];
#pragma unroll
    for (int r = 0; r < 4; ++r) {
      const int row = lg * 4 + r;
      out[(size_t)(row0 + row) * D + col] =
          (ns[row][col] + acc2[nt][r] + ub2v) * msk[row];
    }
  }
}

extern "C" void kernel_launch(void* const* d_in, const int* in_sizes, int n_in,
                              void* d_out, int out_size, void* d_ws, size_t ws_size,
                              hipStream_t stream) {
  (void)in_sizes; (void)n_in; (void)out_size; (void)ws_size;
  const float* nodes     = (const float*)d_in[0];
  const float* node_mask = (const float*)d_in[1];
  const float* ln_g      = (const float*)d_in[2];
  const float* ln_b      = (const float*)d_in[3];
  const float* mw1       = (const float*)d_in[4];
  const float* mb1       = (const float*)d_in[5];
  const float* mw2       = (const float*)d_in[6];
  const float* mb2       = (const float*)d_in[7];
  const float* uw1       = (const float*)d_in[8];
  const float* ub1       = (const float*)d_in[9];
  const float* uw2       = (const float*)d_in[10];
  const float* ub2       = (const float*)d_in[11];
  float* out = (float*)d_out;

  char* ws = (char*)d_ws;
  float*          xi_p = (float*)(ws);                               // 4 MB
  unsigned short* xjh  = (unsigned short*)(ws + ((size_t)4 << 20));  // 2 MB
  float*          agg  = (float*)(ws + ((size_t)6 << 20));           // 2 MB
  unsigned short* bw2  = (unsigned short*)(ws + ((size_t)8 << 20));            // 64 KB
  unsigned short* w1f  = (unsigned short*)(ws + ((size_t)8 << 20) + (64 << 10));   // 128 KB
  unsigned short* w3f  = (unsigned short*)(ws + ((size_t)8 << 20) + (192 << 10));  // 128 KB
  unsigned short* w4f  = (unsigned short*)(ws + ((size_t)8 << 20) + (320 << 10));  // 64 KB

  k_repack<<<48, 512, 0, stream>>>(mw1, uw1, uw2, mw2, w1f, w3f, w4f, bw2);
  k_ln_proj<<<dim3(256, 2), 256, 0, stream>>>(nodes, node_mask, ln_g, ln_b, w1f, xi_p, xjh);
  k_msgs<<<dim3(NN / 2, NB), 512, 0, stream>>>(xi_p, xjh, bw2, mb1, mb2, node_mask, agg);
  k_upd<<<256, 256, 0, stream>>>(nodes, agg, w3f, ub1, w4f, ub2, node_mask, out);
}